// Round 3
// baseline (227.363 us; speedup 1.0000x reference)
//
#include <hip/hip_runtime.h>
#include <hip/hip_bf16.h>
#include <cstdint>
#include <cstddef>

#define N_NODES 50000
#define DEG     24
#define NEDGE   (N_NODES*DEG)
#define RSZ     500
#define NDIM    64
#define FEATD   192

// LDS row stride (shorts) for the 16x200 per-wave buffers in k_gate.
#define LSTR    200

// Fallback k_layer grid (global-memory reln): 32 nodes/block, XCD swizzle.
#define LGRID   1568
#define LCHUNK  196

// LDS-staged k_layer: 256 blocks x 1024 threads, 1 block/CU, 196 nodes/block.
#define NPB     196
#define SREL_STRIDE 68
#define LAYER_LDS_BYTES ((RSZ*SREL_STRIDE + RSZ) * 4)   // 138000

typedef short bf16x8 __attribute__((ext_vector_type(8)));
typedef float f32x4  __attribute__((ext_vector_type(4)));

__device__ __forceinline__ unsigned short f2bf(float f) {
    unsigned u = __builtin_bit_cast(unsigned, f);
    unsigned r = (u + 0x7fffu + ((u >> 16) & 1u)) >> 16;   // RNE
    return (unsigned short)r;
}
__device__ __forceinline__ float bf2f(unsigned short s) {
    unsigned u = ((unsigned)s) << 16;
    return __builtin_bit_cast(float, u);
}
__device__ __forceinline__ float lo16(unsigned u) {
    return __builtin_bit_cast(float, u << 16);
}
__device__ __forceinline__ float hi16(unsigned u) {
    return __builtin_bit_cast(float, u & 0xFFFF0000u);
}
__device__ __forceinline__ float fast_tanh(float x) {
    float e = __expf(2.f * x);
    return 1.f - 2.f / (e + 1.f);
}

// ---- PREP (fused) -----------------------------------------------------------
__global__ __launch_bounds__(256) void k_prep(const float* __restrict__ features,
                                              const float* __restrict__ rel_emb,
                                              const float* __restrict__ attn_k,
                                              const float* __restrict__ proxy,
                                              const float* __restrict__ gate_w,
                                              const int* __restrict__ src,
                                              const int* __restrict__ rel,
                                              unsigned short* __restrict__ fin0,
                                              float* __restrict__ reln,
                                              float* __restrict__ expdot,
                                              float* __restrict__ pninv,
                                              unsigned short* __restrict__ B1,
                                              unsigned short* __restrict__ B2,
                                              unsigned short* __restrict__ B3,
                                              unsigned int* __restrict__ pedge) {
    int b = blockIdx.x;
    if (b < 3125) {
        int t = b * 256 + threadIdx.x;
        int idx4 = t * 4;
        float4 f = *reinterpret_cast<const float4*>(features + idx4);
        uint2 w;
        w.x = (unsigned)f2bf(fast_tanh(f.x)) | ((unsigned)f2bf(fast_tanh(f.y)) << 16);
        w.y = (unsigned)f2bf(fast_tanh(f.z)) | ((unsigned)f2bf(fast_tanh(f.w)) << 16);
        *reinterpret_cast<uint2*>(fin0 + idx4) = w;
    } else if (b < 3250) {
        int lane = threadIdx.x & 63;
        int row = (b - 3125) * 4 + (threadIdx.x >> 6);   // 500 rows
        float v = rel_emb[row * 64 + lane];
        float ss = v * v;
        for (int m = 1; m < 64; m <<= 1) ss += __shfl_xor(ss, m);
        float inv = 1.f / fmaxf(sqrtf(ss), 1e-12f);
        float rn = v * inv;
        reln[row * 64 + lane] = rn;
        float d0 = rn * attn_k[lane];
        float d1 = rn * attn_k[64 + lane];
        for (int m = 1; m < 64; m <<= 1) { d0 += __shfl_xor(d0, m); d1 += __shfl_xor(d1, m); }
        if (lane == 0) { expdot[row] = __expf(d0); expdot[RSZ + row] = __expf(d1); }
    } else if (b < 3266) {
        int lane = threadIdx.x & 63;
        int row = (b - 3250) * 4 + (threadIdx.x >> 6);   // 64 rows
        const float* p = proxy + (size_t)row * FEATD;
        float a = p[lane], bb = p[64 + lane], c = p[128 + lane];
        float ss = a * a + bb * bb + c * c;
        for (int m = 1; m < 64; m <<= 1) ss += __shfl_xor(ss, m);
        if (lane == 0) pninv[row] = 1.f / fmaxf(sqrtf(ss), 1e-12f);
    } else if (b < 3506) {
        int idx = (b - 3266) * 256 + threadIdx.x;
        int j = idx & 7, lane = (idx >> 3) & 63;
        int t = idx >> 9;
        int lane16 = lane & 15, quad = lane >> 4;
        if (t < 24) {
            int kt = t >> 2, nt = t & 3;
            int k = kt * 32 + quad * 8 + j, n = nt * 16 + lane16;
            B1[idx] = f2bf(proxy[(size_t)n * FEATD + k]);
        } else if (t < 48) {
            int tt = t - 24, kt = tt / 12, nt = tt % 12;
            int k = kt * 32 + quad * 8 + j, n = nt * 16 + lane16;
            B2[idx - 12288] = f2bf(proxy[(size_t)k * FEATD + n]);
        } else {
            int tt = t - 48, kt = tt / 12, nt = tt % 12;
            int k = kt * 32 + quad * 8 + j, n = nt * 16 + lane16;
            B3[idx - 24576] = f2bf(gate_w[(size_t)n * FEATD + k]);
        }
    } else {
        int t = (b - 3506) * 256 + threadIdx.x;
        if (t < NEDGE / 4) {
            int4 s4 = *reinterpret_cast<const int4*>(src + t * 4);
            int4 r4 = *reinterpret_cast<const int4*>(rel + t * 4);
            uint4 o;
            o.x = (unsigned)s4.x | ((unsigned)r4.x << 16);
            o.y = (unsigned)s4.y | ((unsigned)r4.y << 16);
            o.z = (unsigned)s4.z | ((unsigned)r4.z << 16);
            o.w = (unsigned)s4.w | ((unsigned)r4.w << 16);
            *reinterpret_cast<uint4*>(pedge + t * 4) = o;
        }
    }
}

// ---- Layer v2: LDS-staged reln/expdot (kept from R1, neutral-to-better) ----
__global__ __launch_bounds__(1024) void k_layer_lds(const unsigned int* __restrict__ pedge,
                                                    const float* __restrict__ reln,
                                                    const float* __restrict__ expdot_l,
                                                    const unsigned short* __restrict__ fin,
                                                    unsigned short* __restrict__ fout) {
    extern __shared__ float smem[];
    float* srel = smem;                       // [RSZ][SREL_STRIDE]
    float* sexp = smem + RSZ * SREL_STRIDE;   // [RSZ]
    {
        const float4* s4 = reinterpret_cast<const float4*>(reln);
        for (int i = threadIdx.x; i < RSZ * 16; i += 1024) {
            int row = i >> 4, c4 = i & 15;
            *reinterpret_cast<float4*>(srel + row * SREL_STRIDE + c4 * 4) = s4[i];
        }
        for (int i = threadIdx.x; i < RSZ; i += 1024) sexp[i] = expdot_l[i];
    }
    __syncthreads();
    int b = blockIdx.x;
    int lb = (b & 7) * 32 + (b >> 3);
    int base = lb * NPB;
    int lane8 = threadIdx.x & 7;
    for (int local = threadIdx.x >> 3; local < NPB; local += 128) {
        int node = base + local;
        if (node >= N_NODES) break;
        int ebase = node * DEG;
        unsigned pk[DEG];
#pragma unroll
        for (int k = 0; k < DEG; k++) pk[k] = pedge[ebase + k];
        float a0 = 0.f, a1 = 0.f, a2 = 0.f, a3 = 0.f;
        float a4 = 0.f, a5 = 0.f, a6 = 0.f, a7 = 0.f, den = 0.f;
#pragma unroll 2
        for (int k = 0; k < DEG; k++) {
            unsigned p = pk[k];
            int s = p & 0xFFFF;
            int r = p >> 16;
            float ex = sexp[r];
            const float* tp = srel + r * SREL_STRIDE + lane8 * 8;
            float4 t0 = *reinterpret_cast<const float4*>(tp);
            float4 t1v = *reinterpret_cast<const float4*>(tp + 4);
            uint4 u = *reinterpret_cast<const uint4*>(fin + (size_t)s * 64 + lane8 * 8);
            float n0 = lo16(u.x), n1 = hi16(u.x), n2 = lo16(u.y), n3 = hi16(u.y);
            float n4 = lo16(u.z), n5 = hi16(u.z), n6 = lo16(u.w), n7 = hi16(u.w);
            float pd = t0.x * n0 + t0.y * n1 + t0.z * n2 + t0.w * n3
                     + t1v.x * n4 + t1v.y * n5 + t1v.z * n6 + t1v.w * n7;
            pd += __shfl_xor(pd, 1); pd += __shfl_xor(pd, 2); pd += __shfl_xor(pd, 4);
            float t1 = -2.f * pd * ex;
            a0 = fmaf(ex, n0, fmaf(t1, t0.x, a0));
            a1 = fmaf(ex, n1, fmaf(t1, t0.y, a1));
            a2 = fmaf(ex, n2, fmaf(t1, t0.z, a2));
            a3 = fmaf(ex, n3, fmaf(t1, t0.w, a3));
            a4 = fmaf(ex, n4, fmaf(t1, t1v.x, a4));
            a5 = fmaf(ex, n5, fmaf(t1, t1v.y, a5));
            a6 = fmaf(ex, n6, fmaf(t1, t1v.z, a6));
            a7 = fmaf(ex, n7, fmaf(t1, t1v.w, a7));
            den += ex;
        }
        float id = 1.f / den;
        uint4 w;
        w.x = (unsigned)f2bf(fast_tanh(a0 * id)) | ((unsigned)f2bf(fast_tanh(a1 * id)) << 16);
        w.y = (unsigned)f2bf(fast_tanh(a2 * id)) | ((unsigned)f2bf(fast_tanh(a3 * id)) << 16);
        w.z = (unsigned)f2bf(fast_tanh(a4 * id)) | ((unsigned)f2bf(fast_tanh(a5 * id)) << 16);
        w.w = (unsigned)f2bf(fast_tanh(a6 * id)) | ((unsigned)f2bf(fast_tanh(a7 * id)) << 16);
        *reinterpret_cast<uint4*>(fout + (size_t)node * 64 + lane8 * 8) = w;
    }
}

// ---- Layer (fallback, global reln) -----------------------------------------
__global__ __launch_bounds__(256) void k_layer(const unsigned int* __restrict__ pedge,
                                               const float* __restrict__ reln,
                                               const float* __restrict__ expdot_l,
                                               const unsigned short* __restrict__ fin,
                                               unsigned short* __restrict__ fout) {
    int b = blockIdx.x;
    int lb = (b & 7) * LCHUNK + (b >> 3);
    int lane8 = threadIdx.x & 7;
    int node = lb * 32 + (threadIdx.x >> 3);
    if (node >= N_NODES) return;
    int ebase = node * DEG;
    unsigned pk[DEG];
#pragma unroll
    for (int k = 0; k < DEG; k++) pk[k] = pedge[ebase + k];
    float a0 = 0.f, a1 = 0.f, a2 = 0.f, a3 = 0.f;
    float a4 = 0.f, a5 = 0.f, a6 = 0.f, a7 = 0.f, den = 0.f;
#pragma unroll 4
    for (int k = 0; k < DEG; k++) {
        unsigned p = pk[k];
        int s = p & 0xFFFF;
        int r = p >> 16;
        float ex = expdot_l[r];
        const float* tp = reln + (size_t)r * 64 + lane8 * 8;
        float4 t0 = *reinterpret_cast<const float4*>(tp);
        float4 t1v = *reinterpret_cast<const float4*>(tp + 4);
        uint4 u = *reinterpret_cast<const uint4*>(fin + (size_t)s * 64 + lane8 * 8);
        float n0 = lo16(u.x), n1 = hi16(u.x), n2 = lo16(u.y), n3 = hi16(u.y);
        float n4 = lo16(u.z), n5 = hi16(u.z), n6 = lo16(u.w), n7 = hi16(u.w);
        float pd = t0.x * n0 + t0.y * n1 + t0.z * n2 + t0.w * n3
                 + t1v.x * n4 + t1v.y * n5 + t1v.z * n6 + t1v.w * n7;
        pd += __shfl_xor(pd, 1); pd += __shfl_xor(pd, 2); pd += __shfl_xor(pd, 4);
        float t1 = -2.f * pd * ex;
        a0 = fmaf(ex, n0, fmaf(t1, t0.x, a0));
        a1 = fmaf(ex, n1, fmaf(t1, t0.y, a1));
        a2 = fmaf(ex, n2, fmaf(t1, t0.z, a2));
        a3 = fmaf(ex, n3, fmaf(t1, t0.w, a3));
        a4 = fmaf(ex, n4, fmaf(t1, t1v.x, a4));
        a5 = fmaf(ex, n5, fmaf(t1, t1v.y, a5));
        a6 = fmaf(ex, n6, fmaf(t1, t1v.z, a6));
        a7 = fmaf(ex, n7, fmaf(t1, t1v.w, a7));
        den += ex;
    }
    float id = 1.f / den;
    uint4 w;
    w.x = (unsigned)f2bf(fast_tanh(a0 * id)) | ((unsigned)f2bf(fast_tanh(a1 * id)) << 16);
    w.y = (unsigned)f2bf(fast_tanh(a2 * id)) | ((unsigned)f2bf(fast_tanh(a3 * id)) << 16);
    w.z = (unsigned)f2bf(fast_tanh(a4 * id)) | ((unsigned)f2bf(fast_tanh(a5 * id)) << 16);
    w.w = (unsigned)f2bf(fast_tanh(a6 * id)) | ((unsigned)f2bf(fast_tanh(a7 * id)) << 16);
    *reinterpret_cast<uint4*>(fout + (size_t)node * 64 + lane8 * 8) = w;
}

// ---- GATE v2: O-tile in LDS, no oreg register array -------------------------
// R2 theory: oreg[12][4] (48 f32) live across the whole kernel forced the
// compiler past 92 VGPR -> it sank/remat'd the 48 scalar global ushort loads
// into the pf phase + epilogue (L2 latency, serialized, 3 waves/SIMD ->
// nothing to hide it). Fix: the O-tile is exactly the same data as af[6];
// write it ONCE to per-wave LDS (6x ds_write_b128) and re-read as u16 LDS
// loads where C-layout values are needed. Kills the scalar global loads and
// the register cliff. Same math bit-for-bit (O passes through as bf16 raw).
__global__ __launch_bounds__(256) void k_gate(const unsigned short* __restrict__ fin0,
                                              const unsigned short* __restrict__ fin1,
                                              const unsigned short* __restrict__ fin2,
                                              const unsigned short* __restrict__ B1,
                                              const unsigned short* __restrict__ B2,
                                              const unsigned short* __restrict__ B3,
                                              const float* __restrict__ pninv,
                                              const float* __restrict__ gate_b,
                                              float* __restrict__ dout) {
    __shared__ unsigned short lds[4][2][16 * LSTR];   // per-wave: O tile + work buf
    int wv = threadIdx.x >> 6, lane = threadIdx.x & 63;
    int tile = blockIdx.x * 4 + wv;
    if (tile > N_NODES / 16 - 1) tile = N_NODES / 16 - 1;  // dup work, identical writes
    int row0 = tile * 16, lane16 = lane & 15, quad = lane >> 4;
    unsigned short* O = lds[wv][0];
    unsigned short* L = lds[wv][1];
    const unsigned short* fsel[3] = {fin0, fin1, fin2};

    // af: 6x 16B vector loads = the entire 16x192 O-tile; store to LDS once.
    bf16x8 af[6];
    float ss = 0.f;
#pragma unroll
    for (int kt = 0; kt < 6; kt++) {
        const unsigned short* f = fsel[kt >> 1];
        bf16x8 a = *reinterpret_cast<const bf16x8*>(f + (size_t)(row0 + lane16) * 64 + (kt & 1) * 32 + quad * 8);
        af[kt] = a;
        *reinterpret_cast<bf16x8*>(O + lane16 * LSTR + (kt >> 1) * 64 + (kt & 1) * 32 + quad * 8) = a;
#pragma unroll
        for (int i = 0; i < 8; i++) {
            float v = bf2f((unsigned short)a[i]);
            ss = fmaf(v, v, ss);
        }
    }
    ss += __shfl_xor(ss, 16); ss += __shfl_xor(ss, 32);   // full row sumsq at lane&15
    float inv = 1.f / fmaxf(sqrtf(ss), 1e-12f);
    float pni[4];
#pragma unroll
    for (int nt = 0; nt < 4; nt++) pni[nt] = pninv[nt * 16 + lane16];
    f32x4 acc4[4];
#pragma unroll
    for (int nt = 0; nt < 4; nt++) acc4[nt] = (f32x4){0.f, 0.f, 0.f, 0.f};
#pragma unroll
    for (int kt = 0; kt < 6; kt++) {
#pragma unroll
        for (int nt = 0; nt < 4; nt++) {
            bf16x8 bfr = *reinterpret_cast<const bf16x8*>(B1 + ((size_t)(kt * 4 + nt) * 64 + lane) * 8);
            acc4[nt] = __builtin_amdgcn_mfma_f32_16x16x32_bf16(af[kt], bfr, acc4[nt], 0, 0, 0);
        }
    }
    // softmax without max-sub: logits are cosine sims in [-1,1]
#pragma unroll
    for (int r = 0; r < 4; r++) {
        int rowloc = quad * 4 + r;
        float invr = __shfl(inv, rowloc);
        float e0 = __expf(acc4[0][r] * invr * pni[0]);
        float e1 = __expf(acc4[1][r] * invr * pni[1]);
        float e2 = __expf(acc4[2][r] * invr * pni[2]);
        float e3 = __expf(acc4[3][r] * invr * pni[3]);
        float s = e0 + e1 + e2 + e3;
        s += __shfl_xor(s, 1); s += __shfl_xor(s, 2);
        s += __shfl_xor(s, 4); s += __shfl_xor(s, 8);
        float rs = 1.f / s;
        L[rowloc * LSTR + lane16]      = f2bf(e0 * rs);
        L[rowloc * LSTR + 16 + lane16] = f2bf(e1 * rs);
        L[rowloc * LSTR + 32 + lane16] = f2bf(e2 * rs);
        L[rowloc * LSTR + 48 + lane16] = f2bf(e3 * rs);
    }
    __threadfence_block();   // drain pa + O writes (wave-private LDS; no s_barrier)

    f32x4 acc[12];
#pragma unroll
    for (int nt = 0; nt < 12; nt++) acc[nt] = (f32x4){0.f, 0.f, 0.f, 0.f};
#pragma unroll
    for (int kt = 0; kt < 2; kt++) {
        bf16x8 a = *reinterpret_cast<const bf16x8*>(L + lane16 * LSTR + kt * 32 + quad * 8);
#pragma unroll
        for (int nt = 0; nt < 12; nt++) {
            bf16x8 bfr = *reinterpret_cast<const bf16x8*>(B2 + ((size_t)(kt * 12 + nt) * 64 + lane) * 8);
            acc[nt] = __builtin_amdgcn_mfma_f32_16x16x32_bf16(a, bfr, acc[nt], 0, 0, 0);
        }
    }
    __threadfence_block();   // pa reads complete before pf overwrites rows

    // pf = O - pa@proxy, in C-layout; O read back from LDS (u16, short latency)
#pragma unroll
    for (int nt = 0; nt < 12; nt++) {
#pragma unroll
        for (int r = 0; r < 4; r++) {
            int rowloc = quad * 4 + r;
            float o = bf2f(O[rowloc * LSTR + nt * 16 + lane16]);
            L[rowloc * LSTR + nt * 16 + lane16] = f2bf(o - acc[nt][r]);
        }
    }
    __threadfence_block();   // drain pf writes

#pragma unroll
    for (int nt = 0; nt < 12; nt++) acc[nt] = (f32x4){0.f, 0.f, 0.f, 0.f};
#pragma unroll
    for (int kt = 0; kt < 6; kt++) {
        bf16x8 a = *reinterpret_cast<const bf16x8*>(L + lane16 * LSTR + kt * 32 + quad * 8);
#pragma unroll
        for (int nt = 0; nt < 12; nt++) {
            bf16x8 bfr = *reinterpret_cast<const bf16x8*>(B3 + ((size_t)(kt * 12 + nt) * 64 + lane) * 8);
            acc[nt] = __builtin_amdgcn_mfma_f32_16x16x32_bf16(a, bfr, acc[nt], 0, 0, 0);
        }
    }

#pragma unroll
    for (int nt = 0; nt < 12; nt++) {
        float bias = gate_b[nt * 16 + lane16];
#pragma unroll
        for (int r = 0; r < 4; r++) {
            int rowloc = quad * 4 + r;
            size_t idx = (size_t)(row0 + rowloc) * FEATD + nt * 16 + lane16;
            float z = acc[nt][r] + bias;
            float g = 1.f / (1.f + __expf(-z));
            float o  = bf2f(O[rowloc * LSTR + nt * 16 + lane16]);
            float pf = bf2f(L[rowloc * LSTR + nt * 16 + lane16]);
            dout[idx] = pf + g * (o - pf);
        }
    }
}

extern "C" void kernel_launch(void* const* d_in, const int* in_sizes, int n_in,
                              void* d_out, int out_size, void* d_ws, size_t ws_size,
                              hipStream_t stream) {
    (void)in_sizes; (void)n_in; (void)out_size; (void)ws_size;
    const float* features = (const float*)d_in[0];
    const float* rel_emb  = (const float*)d_in[1];
    const float* proxy    = (const float*)d_in[2];
    const float* gate_w   = (const float*)d_in[3];
    const float* gate_b   = (const float*)d_in[4];
    const float* attn_k   = (const float*)d_in[5];
    const int*   adj      = (const int*)d_in[6];
    const int*   r_index  = (const int*)d_in[7];
    // d_in[8] (r_val) unused: positive scale cancels under l2norm; r_index[0]==arange(E).

    unsigned short* fin0 = (unsigned short*)d_ws;           // N*64 bf16
    unsigned short* fin1 = fin0 + (size_t)N_NODES * 64;     // N*64 bf16
    unsigned short* fin2 = fin1 + (size_t)N_NODES * 64;     // N*64 bf16
    float* reln    = (float*)(fin2 + (size_t)N_NODES * 64); // 500*64 fp32
    float* expdot  = reln + RSZ * 64;                       // 2*500
    float* pninv   = expdot + 2 * RSZ;                      // 64
    unsigned short* B1 = (unsigned short*)(pninv + 64);     // 12288
    unsigned short* B2 = B1 + 12288;                        // 12288
    unsigned short* B3 = B2 + 12288;                        // 36864
    unsigned int* pedge = (unsigned int*)(B3 + 36864);      // NEDGE u32

    const int* src = adj + NEDGE;       // adj[1]
    const int* rel = r_index + NEDGE;   // r_index[1]

    // One-time opt-in to >64KB dynamic LDS for the staged layer kernel.
    static int lds_mode = -1;
    if (lds_mode < 0) {
        hipError_t e = hipFuncSetAttribute((const void*)k_layer_lds,
                                           hipFuncAttributeMaxDynamicSharedMemorySize,
                                           LAYER_LDS_BYTES);
        lds_mode = (e == hipSuccess) ? 1 : 0;
    }

    k_prep  <<<dim3(4678), dim3(256), 0, stream>>>(features, rel_emb, attn_k, proxy, gate_w,
                                                   src, rel, fin0, reln, expdot,
                                                   pninv, B1, B2, B3, pedge);
    if (lds_mode == 1) {
        k_layer_lds <<<dim3(256), dim3(1024), LAYER_LDS_BYTES, stream>>>(pedge, reln, expdot,       fin0, fin1);
        k_layer_lds <<<dim3(256), dim3(1024), LAYER_LDS_BYTES, stream>>>(pedge, reln, expdot + RSZ, fin1, fin2);
    } else {
        k_layer <<<dim3(LGRID), dim3(256), 0, stream>>>(pedge, reln, expdot,       fin0, fin1);
        k_layer <<<dim3(LGRID), dim3(256), 0, stream>>>(pedge, reln, expdot + RSZ, fin1, fin2);
    }
    k_gate  <<<dim3(782),  dim3(256), 0, stream>>>(fin0, fin1, fin2, B1, B2, B3, pninv,
                                                   gate_b, (float*)d_out);
}

// Round 4
// 170.965 us; speedup vs baseline: 1.3299x; 1.3299x over previous
//
#include <hip/hip_runtime.h>
#include <hip/hip_bf16.h>
#include <cstdint>
#include <cstddef>

#define N_NODES 50000
#define DEG     24
#define NEDGE   (N_NODES*DEG)
#define RSZ     500
#define NDIM    64
#define FEATD   192

// LDS row stride (shorts) for the 16x200 per-wave transpose buffer in k_gate.
#define LSTR    200

// Fallback k_layer grid (global-memory reln): 32 nodes/block, XCD swizzle.
#define LGRID   1568
#define LCHUNK  196

// LDS-staged k_layer: 256 blocks x 1024 threads, 1 block/CU, 196 nodes/block.
#define NPB     196
#define SREL_STRIDE 68
#define LAYER_LDS_BYTES ((RSZ*SREL_STRIDE + RSZ) * 4)   // 138000

typedef short bf16x8 __attribute__((ext_vector_type(8)));
typedef float f32x4  __attribute__((ext_vector_type(4)));

__device__ __forceinline__ unsigned short f2bf(float f) {
    unsigned u = __builtin_bit_cast(unsigned, f);
    unsigned r = (u + 0x7fffu + ((u >> 16) & 1u)) >> 16;   // RNE
    return (unsigned short)r;
}
__device__ __forceinline__ float bf2f(unsigned short s) {
    unsigned u = ((unsigned)s) << 16;
    return __builtin_bit_cast(float, u);
}
__device__ __forceinline__ float lo16(unsigned u) {
    return __builtin_bit_cast(float, u << 16);
}
__device__ __forceinline__ float hi16(unsigned u) {
    return __builtin_bit_cast(float, u & 0xFFFF0000u);
}
__device__ __forceinline__ float fast_tanh(float x) {
    float e = __expf(2.f * x);
    return 1.f - 2.f / (e + 1.f);
}

// ---- PREP (fused) -----------------------------------------------------------
__global__ __launch_bounds__(256) void k_prep(const float* __restrict__ features,
                                              const float* __restrict__ rel_emb,
                                              const float* __restrict__ attn_k,
                                              const float* __restrict__ proxy,
                                              const float* __restrict__ gate_w,
                                              const int* __restrict__ src,
                                              const int* __restrict__ rel,
                                              unsigned short* __restrict__ fin0,
                                              float* __restrict__ reln,
                                              float* __restrict__ expdot,
                                              float* __restrict__ pninv,
                                              unsigned short* __restrict__ B1,
                                              unsigned short* __restrict__ B2,
                                              unsigned short* __restrict__ B3,
                                              unsigned int* __restrict__ pedge) {
    int b = blockIdx.x;
    if (b < 3125) {
        int t = b * 256 + threadIdx.x;
        int idx4 = t * 4;
        float4 f = *reinterpret_cast<const float4*>(features + idx4);
        uint2 w;
        w.x = (unsigned)f2bf(fast_tanh(f.x)) | ((unsigned)f2bf(fast_tanh(f.y)) << 16);
        w.y = (unsigned)f2bf(fast_tanh(f.z)) | ((unsigned)f2bf(fast_tanh(f.w)) << 16);
        *reinterpret_cast<uint2*>(fin0 + idx4) = w;
    } else if (b < 3250) {
        int lane = threadIdx.x & 63;
        int row = (b - 3125) * 4 + (threadIdx.x >> 6);   // 500 rows
        float v = rel_emb[row * 64 + lane];
        float ss = v * v;
        for (int m = 1; m < 64; m <<= 1) ss += __shfl_xor(ss, m);
        float inv = 1.f / fmaxf(sqrtf(ss), 1e-12f);
        float rn = v * inv;
        reln[row * 64 + lane] = rn;
        float d0 = rn * attn_k[lane];
        float d1 = rn * attn_k[64 + lane];
        for (int m = 1; m < 64; m <<= 1) { d0 += __shfl_xor(d0, m); d1 += __shfl_xor(d1, m); }
        if (lane == 0) { expdot[row] = __expf(d0); expdot[RSZ + row] = __expf(d1); }
    } else if (b < 3266) {
        int lane = threadIdx.x & 63;
        int row = (b - 3250) * 4 + (threadIdx.x >> 6);   // 64 rows
        const float* p = proxy + (size_t)row * FEATD;
        float a = p[lane], bb = p[64 + lane], c = p[128 + lane];
        float ss = a * a + bb * bb + c * c;
        for (int m = 1; m < 64; m <<= 1) ss += __shfl_xor(ss, m);
        if (lane == 0) pninv[row] = 1.f / fmaxf(sqrtf(ss), 1e-12f);
    } else if (b < 3506) {
        int idx = (b - 3266) * 256 + threadIdx.x;
        int j = idx & 7, lane = (idx >> 3) & 63;
        int t = idx >> 9;
        int lane16 = lane & 15, quad = lane >> 4;
        if (t < 24) {
            int kt = t >> 2, nt = t & 3;
            int k = kt * 32 + quad * 8 + j, n = nt * 16 + lane16;
            B1[idx] = f2bf(proxy[(size_t)n * FEATD + k]);
        } else if (t < 48) {
            int tt = t - 24, kt = tt / 12, nt = tt % 12;
            int k = kt * 32 + quad * 8 + j, n = nt * 16 + lane16;
            B2[idx - 12288] = f2bf(proxy[(size_t)k * FEATD + n]);
        } else {
            int tt = t - 48, kt = tt / 12, nt = tt % 12;
            int k = kt * 32 + quad * 8 + j, n = nt * 16 + lane16;
            B3[idx - 24576] = f2bf(gate_w[(size_t)n * FEATD + k]);
        }
    } else {
        int t = (b - 3506) * 256 + threadIdx.x;
        if (t < NEDGE / 4) {
            int4 s4 = *reinterpret_cast<const int4*>(src + t * 4);
            int4 r4 = *reinterpret_cast<const int4*>(rel + t * 4);
            uint4 o;
            o.x = (unsigned)s4.x | ((unsigned)r4.x << 16);
            o.y = (unsigned)s4.y | ((unsigned)r4.y << 16);
            o.z = (unsigned)s4.z | ((unsigned)r4.z << 16);
            o.w = (unsigned)s4.w | ((unsigned)r4.w << 16);
            *reinterpret_cast<uint4*>(pedge + t * 4) = o;
        }
    }
}

// ---- Layer v3: LDS-staged reln/expdot + BATCHED edge loads ------------------
// R4: edges processed 4 at a time; the 4x(sexp + srel + fin) loads issue as a
// batch (12 independent loads in flight) instead of serializing one edge at a
// time at load latency. pedge fetched as uint4 one batch ahead.
__global__ __launch_bounds__(1024, 1) void k_layer_lds(const unsigned int* __restrict__ pedge,
                                                       const float* __restrict__ reln,
                                                       const float* __restrict__ expdot_l,
                                                       const unsigned short* __restrict__ fin,
                                                       unsigned short* __restrict__ fout) {
    extern __shared__ float smem[];
    float* srel = smem;                       // [RSZ][SREL_STRIDE]
    float* sexp = smem + RSZ * SREL_STRIDE;   // [RSZ]
    {
        const float4* s4 = reinterpret_cast<const float4*>(reln);
        for (int i = threadIdx.x; i < RSZ * 16; i += 1024) {
            int row = i >> 4, c4 = i & 15;
            *reinterpret_cast<float4*>(srel + row * SREL_STRIDE + c4 * 4) = s4[i];
        }
        for (int i = threadIdx.x; i < RSZ; i += 1024) sexp[i] = expdot_l[i];
    }
    __syncthreads();
    int b = blockIdx.x;
    int lb = (b & 7) * 32 + (b >> 3);         // XCD owns contiguous node range
    int base = lb * NPB;
    int lane8 = threadIdx.x & 7;
    for (int local = threadIdx.x >> 3; local < NPB; local += 128) {
        int node = base + local;
        if (node >= N_NODES) break;
        const uint4* pe4 = reinterpret_cast<const uint4*>(pedge + node * DEG);
        float a0 = 0.f, a1 = 0.f, a2 = 0.f, a3 = 0.f;
        float a4 = 0.f, a5 = 0.f, a6 = 0.f, a7 = 0.f, den = 0.f;
        uint4 pc = pe4[0];
#pragma unroll
        for (int kb = 0; kb < DEG / 4; kb++) {
            uint4 pn = pc;
            if (kb < DEG / 4 - 1) pn = pe4[kb + 1];
            unsigned ps[4] = {pc.x, pc.y, pc.z, pc.w};
            float ex[4]; float4 t0[4], t1v[4]; uint4 u[4];
#pragma unroll
            for (int j = 0; j < 4; j++) {
                int s = ps[j] & 0xFFFF;
                int r = ps[j] >> 16;
                ex[j] = sexp[r];
                const float* tp = srel + r * SREL_STRIDE + lane8 * 8;
                t0[j]  = *reinterpret_cast<const float4*>(tp);
                t1v[j] = *reinterpret_cast<const float4*>(tp + 4);
                u[j]   = *reinterpret_cast<const uint4*>(fin + (size_t)s * 64 + lane8 * 8);
            }
#pragma unroll
            for (int j = 0; j < 4; j++) {
                float n0 = lo16(u[j].x), n1 = hi16(u[j].x), n2 = lo16(u[j].y), n3 = hi16(u[j].y);
                float n4 = lo16(u[j].z), n5 = hi16(u[j].z), n6 = lo16(u[j].w), n7 = hi16(u[j].w);
                float pd = t0[j].x * n0 + t0[j].y * n1 + t0[j].z * n2 + t0[j].w * n3
                         + t1v[j].x * n4 + t1v[j].y * n5 + t1v[j].z * n6 + t1v[j].w * n7;
                pd += __shfl_xor(pd, 1); pd += __shfl_xor(pd, 2); pd += __shfl_xor(pd, 4);
                float tc = -2.f * pd * ex[j];          // acc += ex*(nv - 2*dot*tv)
                a0 = fmaf(ex[j], n0, fmaf(tc, t0[j].x, a0));
                a1 = fmaf(ex[j], n1, fmaf(tc, t0[j].y, a1));
                a2 = fmaf(ex[j], n2, fmaf(tc, t0[j].z, a2));
                a3 = fmaf(ex[j], n3, fmaf(tc, t0[j].w, a3));
                a4 = fmaf(ex[j], n4, fmaf(tc, t1v[j].x, a4));
                a5 = fmaf(ex[j], n5, fmaf(tc, t1v[j].y, a5));
                a6 = fmaf(ex[j], n6, fmaf(tc, t1v[j].z, a6));
                a7 = fmaf(ex[j], n7, fmaf(tc, t1v[j].w, a7));
                den += ex[j];
            }
            pc = pn;
        }
        float id = 1.f / den;
        uint4 w;
        w.x = (unsigned)f2bf(fast_tanh(a0 * id)) | ((unsigned)f2bf(fast_tanh(a1 * id)) << 16);
        w.y = (unsigned)f2bf(fast_tanh(a2 * id)) | ((unsigned)f2bf(fast_tanh(a3 * id)) << 16);
        w.z = (unsigned)f2bf(fast_tanh(a4 * id)) | ((unsigned)f2bf(fast_tanh(a5 * id)) << 16);
        w.w = (unsigned)f2bf(fast_tanh(a6 * id)) | ((unsigned)f2bf(fast_tanh(a7 * id)) << 16);
        *reinterpret_cast<uint4*>(fout + (size_t)node * 64 + lane8 * 8) = w;
    }
}

// ---- Layer (fallback, global reln) -----------------------------------------
__global__ __launch_bounds__(256) void k_layer(const unsigned int* __restrict__ pedge,
                                               const float* __restrict__ reln,
                                               const float* __restrict__ expdot_l,
                                               const unsigned short* __restrict__ fin,
                                               unsigned short* __restrict__ fout) {
    int b = blockIdx.x;
    int lb = (b & 7) * LCHUNK + (b >> 3);
    int lane8 = threadIdx.x & 7;
    int node = lb * 32 + (threadIdx.x >> 3);
    if (node >= N_NODES) return;
    int ebase = node * DEG;
    unsigned pk[DEG];
#pragma unroll
    for (int k = 0; k < DEG; k++) pk[k] = pedge[ebase + k];
    float a0 = 0.f, a1 = 0.f, a2 = 0.f, a3 = 0.f;
    float a4 = 0.f, a5 = 0.f, a6 = 0.f, a7 = 0.f, den = 0.f;
#pragma unroll 4
    for (int k = 0; k < DEG; k++) {
        unsigned p = pk[k];
        int s = p & 0xFFFF;
        int r = p >> 16;
        float ex = expdot_l[r];
        const float* tp = reln + (size_t)r * 64 + lane8 * 8;
        float4 t0 = *reinterpret_cast<const float4*>(tp);
        float4 t1v = *reinterpret_cast<const float4*>(tp + 4);
        uint4 u = *reinterpret_cast<const uint4*>(fin + (size_t)s * 64 + lane8 * 8);
        float n0 = lo16(u.x), n1 = hi16(u.x), n2 = lo16(u.y), n3 = hi16(u.y);
        float n4 = lo16(u.z), n5 = hi16(u.z), n6 = lo16(u.w), n7 = hi16(u.w);
        float pd = t0.x * n0 + t0.y * n1 + t0.z * n2 + t0.w * n3
                 + t1v.x * n4 + t1v.y * n5 + t1v.z * n6 + t1v.w * n7;
        pd += __shfl_xor(pd, 1); pd += __shfl_xor(pd, 2); pd += __shfl_xor(pd, 4);
        float t1 = -2.f * pd * ex;
        a0 = fmaf(ex, n0, fmaf(t1, t0.x, a0));
        a1 = fmaf(ex, n1, fmaf(t1, t0.y, a1));
        a2 = fmaf(ex, n2, fmaf(t1, t0.z, a2));
        a3 = fmaf(ex, n3, fmaf(t1, t0.w, a3));
        a4 = fmaf(ex, n4, fmaf(t1, t1v.x, a4));
        a5 = fmaf(ex, n5, fmaf(t1, t1v.y, a5));
        a6 = fmaf(ex, n6, fmaf(t1, t1v.z, a6));
        a7 = fmaf(ex, n7, fmaf(t1, t1v.w, a7));
        den += ex;
    }
    float id = 1.f / den;
    uint4 w;
    w.x = (unsigned)f2bf(fast_tanh(a0 * id)) | ((unsigned)f2bf(fast_tanh(a1 * id)) << 16);
    w.y = (unsigned)f2bf(fast_tanh(a2 * id)) | ((unsigned)f2bf(fast_tanh(a3 * id)) << 16);
    w.z = (unsigned)f2bf(fast_tanh(a4 * id)) | ((unsigned)f2bf(fast_tanh(a5 * id)) << 16);
    w.w = (unsigned)f2bf(fast_tanh(a6 * id)) | ((unsigned)f2bf(fast_tanh(a7 * id)) << 16);
    *reinterpret_cast<uint4*>(fout + (size_t)node * 64 + lane8 * 8) = w;
}

// ---- GATE v3: register oreg (42µs structure) + VGPR headroom + batched B ----
// R3 lesson: grid (782 blk) limits occupancy to ~3 waves/SIMD regardless of
// VGPR, so a small register budget buys nothing and serializes the 120
// B-fragment global loads (each ~L2 latency). launch_bounds(256,3) raises the
// cap to ~168 VGPR (still 3 waves/SIMD); each MFMA phase loads its whole
// B-batch into registers first so loads pipeline under one stall.
__global__ __launch_bounds__(256, 3) void k_gate(const unsigned short* __restrict__ fin0,
                                                 const unsigned short* __restrict__ fin1,
                                                 const unsigned short* __restrict__ fin2,
                                                 const unsigned short* __restrict__ B1,
                                                 const unsigned short* __restrict__ B2,
                                                 const unsigned short* __restrict__ B3,
                                                 const float* __restrict__ pninv,
                                                 const float* __restrict__ gate_b,
                                                 float* __restrict__ dout) {
    __shared__ unsigned short lds[4][16 * LSTR];
    int wv = threadIdx.x >> 6, lane = threadIdx.x & 63;
    int tile = blockIdx.x * 4 + wv;
    if (tile > N_NODES / 16 - 1) tile = N_NODES / 16 - 1;  // dup work, identical writes
    int row0 = tile * 16, lane16 = lane & 15, quad = lane >> 4;
    unsigned short* L = lds[wv];
    const unsigned short* fsel[3] = {fin0, fin1, fin2};

    // o in C-layout (rows quad*4+r, col nt*16+lane16) — independent, issue early
    float oreg[12][4];
#pragma unroll
    for (int nt = 0; nt < 12; nt++) {
        const unsigned short* f = fsel[nt >> 2];
#pragma unroll
        for (int r = 0; r < 4; r++)
            oreg[nt][r] = bf2f(f[(size_t)(row0 + quad * 4 + r) * 64 + (nt & 3) * 16 + lane16]);
    }

    // af: direct 16B bf16 A-fragment loads; sumsq via cvt
    bf16x8 af[6];
    float ss = 0.f;
#pragma unroll
    for (int kt = 0; kt < 6; kt++) {
        const unsigned short* f = fsel[kt >> 1];
        bf16x8 a = *reinterpret_cast<const bf16x8*>(f + (size_t)(row0 + lane16) * 64 + (kt & 1) * 32 + quad * 8);
        af[kt] = a;
#pragma unroll
        for (int i = 0; i < 8; i++) {
            float v = bf2f((unsigned short)a[i]);
            ss = fmaf(v, v, ss);
        }
    }
    ss += __shfl_xor(ss, 16); ss += __shfl_xor(ss, 32);   // full row sumsq at lane&15
    float inv = 1.f / fmaxf(sqrtf(ss), 1e-12f);
    float pni[4];
#pragma unroll
    for (int nt = 0; nt < 4; nt++) pni[nt] = pninv[nt * 16 + lane16];
    f32x4 acc4[4];
#pragma unroll
    for (int nt = 0; nt < 4; nt++) acc4[nt] = (f32x4){0.f, 0.f, 0.f, 0.f};
    // B1 phase: batch 8 fragments (2 kt) per load burst
#pragma unroll
    for (int ktp = 0; ktp < 3; ktp++) {
        bf16x8 bb[8];
#pragma unroll
        for (int h = 0; h < 2; h++)
#pragma unroll
            for (int nt = 0; nt < 4; nt++)
                bb[h * 4 + nt] = *reinterpret_cast<const bf16x8*>(B1 + ((size_t)((ktp * 2 + h) * 4 + nt) * 64 + lane) * 8);
#pragma unroll
        for (int h = 0; h < 2; h++)
#pragma unroll
            for (int nt = 0; nt < 4; nt++)
                acc4[nt] = __builtin_amdgcn_mfma_f32_16x16x32_bf16(af[ktp * 2 + h], bb[h * 4 + nt], acc4[nt], 0, 0, 0);
    }
    // softmax without max-sub: logits are cosine sims in [-1,1]
#pragma unroll
    for (int r = 0; r < 4; r++) {
        int rowloc = quad * 4 + r;
        float invr = __shfl(inv, rowloc);
        float e0 = __expf(acc4[0][r] * invr * pni[0]);
        float e1 = __expf(acc4[1][r] * invr * pni[1]);
        float e2 = __expf(acc4[2][r] * invr * pni[2]);
        float e3 = __expf(acc4[3][r] * invr * pni[3]);
        float s = e0 + e1 + e2 + e3;
        s += __shfl_xor(s, 1); s += __shfl_xor(s, 2);
        s += __shfl_xor(s, 4); s += __shfl_xor(s, 8);
        float rs = 1.f / s;
        L[rowloc * LSTR + lane16]      = f2bf(e0 * rs);
        L[rowloc * LSTR + 16 + lane16] = f2bf(e1 * rs);
        L[rowloc * LSTR + 32 + lane16] = f2bf(e2 * rs);
        L[rowloc * LSTR + 48 + lane16] = f2bf(e3 * rs);
    }
    __threadfence_block();   // drain pa writes (wave-private LDS; no s_barrier)

    f32x4 acc[12];
#pragma unroll
    for (int nt = 0; nt < 12; nt++) acc[nt] = (f32x4){0.f, 0.f, 0.f, 0.f};
    // B2 phase: batch all 12 fragments per kt
#pragma unroll
    for (int kt = 0; kt < 2; kt++) {
        bf16x8 a = *reinterpret_cast<const bf16x8*>(L + lane16 * LSTR + kt * 32 + quad * 8);
        bf16x8 bb[12];
#pragma unroll
        for (int nt = 0; nt < 12; nt++)
            bb[nt] = *reinterpret_cast<const bf16x8*>(B2 + ((size_t)(kt * 12 + nt) * 64 + lane) * 8);
#pragma unroll
        for (int nt = 0; nt < 12; nt++)
            acc[nt] = __builtin_amdgcn_mfma_f32_16x16x32_bf16(a, bb[nt], acc[nt], 0, 0, 0);
    }
    __threadfence_block();   // pa reads complete before pf overwrites rows
#pragma unroll
    for (int nt = 0; nt < 12; nt++) {
#pragma unroll
        for (int r = 0; r < 4; r++) {
            int rowloc = quad * 4 + r;
            L[rowloc * LSTR + nt * 16 + lane16] = f2bf(oreg[nt][r] - acc[nt][r]);
        }
    }
    __threadfence_block();   // drain pf writes

#pragma unroll
    for (int nt = 0; nt < 12; nt++) acc[nt] = (f32x4){0.f, 0.f, 0.f, 0.f};
    // B3 phase: batch all 12 fragments per kt
#pragma unroll
    for (int kt = 0; kt < 6; kt++) {
        bf16x8 a = *reinterpret_cast<const bf16x8*>(L + lane16 * LSTR + kt * 32 + quad * 8);
        bf16x8 bb[12];
#pragma unroll
        for (int nt = 0; nt < 12; nt++)
            bb[nt] = *reinterpret_cast<const bf16x8*>(B3 + ((size_t)(kt * 12 + nt) * 64 + lane) * 8);
#pragma unroll
        for (int nt = 0; nt < 12; nt++)
            acc[nt] = __builtin_amdgcn_mfma_f32_16x16x32_bf16(a, bb[nt], acc[nt], 0, 0, 0);
    }

#pragma unroll
    for (int nt = 0; nt < 12; nt++) {
        float bias = gate_b[nt * 16 + lane16];
#pragma unroll
        for (int r = 0; r < 4; r++) {
            int rowloc = quad * 4 + r;
            size_t idx = (size_t)(row0 + rowloc) * FEATD + nt * 16 + lane16;
            float z = acc[nt][r] + bias;
            float g = 1.f / (1.f + __expf(-z));
            float pf = bf2f(L[rowloc * LSTR + nt * 16 + lane16]);
            dout[idx] = pf + g * (oreg[nt][r] - pf);
        }
    }
}

extern "C" void kernel_launch(void* const* d_in, const int* in_sizes, int n_in,
                              void* d_out, int out_size, void* d_ws, size_t ws_size,
                              hipStream_t stream) {
    (void)in_sizes; (void)n_in; (void)out_size; (void)ws_size;
    const float* features = (const float*)d_in[0];
    const float* rel_emb  = (const float*)d_in[1];
    const float* proxy    = (const float*)d_in[2];
    const float* gate_w   = (const float*)d_in[3];
    const float* gate_b   = (const float*)d_in[4];
    const float* attn_k   = (const float*)d_in[5];
    const int*   adj      = (const int*)d_in[6];
    const int*   r_index  = (const int*)d_in[7];
    // d_in[8] (r_val) unused: positive scale cancels under l2norm; r_index[0]==arange(E).

    unsigned short* fin0 = (unsigned short*)d_ws;           // N*64 bf16
    unsigned short* fin1 = fin0 + (size_t)N_NODES * 64;     // N*64 bf16
    unsigned short* fin2 = fin1 + (size_t)N_NODES * 64;     // N*64 bf16
    float* reln    = (float*)(fin2 + (size_t)N_NODES * 64); // 500*64 fp32
    float* expdot  = reln + RSZ * 64;                       // 2*500
    float* pninv   = expdot + 2 * RSZ;                      // 64
    unsigned short* B1 = (unsigned short*)(pninv + 64);     // 12288
    unsigned short* B2 = B1 + 12288;                        // 12288
    unsigned short* B3 = B2 + 12288;                        // 36864
    unsigned int* pedge = (unsigned int*)(B3 + 36864);      // NEDGE u32

    const int* src = adj + NEDGE;       // adj[1]
    const int* rel = r_index + NEDGE;   // r_index[1]

    // One-time opt-in to >64KB dynamic LDS for the staged layer kernel.
    static int lds_mode = -1;
    if (lds_mode < 0) {
        hipError_t e = hipFuncSetAttribute((const void*)k_layer_lds,
                                           hipFuncAttributeMaxDynamicSharedMemorySize,
                                           LAYER_LDS_BYTES);
        lds_mode = (e == hipSuccess) ? 1 : 0;
    }

    k_prep  <<<dim3(4678), dim3(256), 0, stream>>>(features, rel_emb, attn_k, proxy, gate_w,
                                                   src, rel, fin0, reln, expdot,
                                                   pninv, B1, B2, B3, pedge);
    if (lds_mode == 1) {
        k_layer_lds <<<dim3(256), dim3(1024), LAYER_LDS_BYTES, stream>>>(pedge, reln, expdot,       fin0, fin1);
        k_layer_lds <<<dim3(256), dim3(1024), LAYER_LDS_BYTES, stream>>>(pedge, reln, expdot + RSZ, fin1, fin2);
    } else {
        k_layer <<<dim3(LGRID), dim3(256), 0, stream>>>(pedge, reln, expdot,       fin0, fin1);
        k_layer <<<dim3(LGRID), dim3(256), 0, stream>>>(pedge, reln, expdot + RSZ, fin1, fin2);
    }
    k_gate  <<<dim3(782),  dim3(256), 0, stream>>>(fin0, fin1, fin2, B1, B2, B3, pninv,
                                                   gate_b, (float*)d_out);
}